// Round 2
// baseline (471.284 us; speedup 1.0000x reference)
//
#include <hip/hip_runtime.h>

#define CDIM 192
#define NHEAD 6

typedef __bf16 bf16x8 __attribute__((ext_vector_type(8)));
typedef float f32x4 __attribute__((ext_vector_type(4)));
typedef unsigned short u16x4 __attribute__((ext_vector_type(4)));

// ---- LDS layout (byte offsets), total 147456 B ----
#define X_OFF   0           // x_win bf16: 64 x 200 = 25600 B
#define QK_OFF  25600       // q,k token-major: 64 x 392 bf16 (cols 0..383)  | later: out f32 64 x 196
#define VT_OFF  75776       // v transposed: 192 x 72 bf16 = 27648 B
#define AO_OFF  103424      // attn out token-major: 64 x 200 bf16
#define P_OFF   129024      // P scratch: 8 waves x (16 x 72) bf16 = 18432 B
#define SMEM_BYTES 147456

#define XS  200   // bf16-elem strides; dword-stride %32 == 4 -> <=2-way banks (free)
#define QKS 392
#define VTS 72
#define AOS 200
#define PS  72
#define OFS 196   // f32 out staging stride (dwords), 196%32==4
#define SCALE 0.17677669529663687f   // 32^-0.5

// ---- d_ws layout (bytes) ----
#define WS_W1   0           // qkv_w bf16: 110592 u16 = 221184 B
#define WS_W2   221184      // proj_w bf16: 36864 u16 = 73728 B
#define WS_B1   294912      // qkv_b f32: 2304 B
#define WS_B2   297216      // proj_b f32: 768 B
#define WS_BIAS 297984      // bias f32: 6*64*64*4 = 98304 B  (total 396288 B)

__device__ __forceinline__ unsigned short f2b(float f) {
    unsigned int u = __float_as_uint(f);
    u = (u + 0x7FFFu + ((u >> 16) & 1u)) >> 16;   // RNE
    return (unsigned short)u;
}

// One-shot per launch: bf16 weight copies + window-independent bias table.
__global__ void prep(const float* __restrict__ qkv_w, const float* __restrict__ qkv_b,
                     const float* __restrict__ proj_w, const float* __restrict__ proj_b,
                     const float* __restrict__ rpb,
                     unsigned short* __restrict__ W1, unsigned short* __restrict__ W2,
                     float* __restrict__ B1, float* __restrict__ B2,
                     float* __restrict__ BIAS) {
    int t = blockIdx.x * 256 + threadIdx.x;       // 0..172799
    if (t < 110592) { W1[t] = f2b(qkv_w[t]); return; }
    t -= 110592;
    if (t < 36864)  { W2[t] = f2b(proj_w[t]); return; }
    t -= 36864;
    if (t < 576)    { B1[t] = qkv_b[t]; return; }
    t -= 576;
    if (t < 192)    { B2[t] = proj_b[t]; return; }
    t -= 192;
    {   // bias[h][i][j], 6*64*64
        int h = t >> 12, ij = t & 4095;
        int i = ij >> 6, j = ij & 63;
        int idx = ((i >> 3) - (j >> 3) + 7) * 15 + ((i & 7) - (j & 7) + 7);
        BIAS[t] = rpb[idx * NHEAD + h];
    }
}

__global__ __launch_bounds__(512, 1)
void win_attn(const float* __restrict__ x,
              const unsigned short* __restrict__ qkv_w,   // bf16 (ws copy)
              const float* __restrict__ qkv_b,
              const unsigned short* __restrict__ proj_w,  // bf16 (ws copy)
              const float* __restrict__ proj_b,
              const float* __restrict__ bias,
              float* __restrict__ out)
{
    extern __shared__ __align__(16) char smem[];
    unsigned short* xl = (unsigned short*)(smem + X_OFF);
    unsigned short* qk = (unsigned short*)(smem + QK_OFF);
    unsigned short* vt = (unsigned short*)(smem + VT_OFF);
    unsigned short* ao = (unsigned short*)(smem + AO_OFF);
    unsigned short* pl = (unsigned short*)(smem + P_OFF);
    float*        outf = (float*)(smem + QK_OFF);         // aliases dead q/k in proj phase

    const int tid  = threadIdx.x;
    const int wv   = tid >> 6;
    const int lane = tid & 63;
    const int l15  = lane & 15;
    const int g    = lane >> 4;
    const int g8   = g << 3;

    const int wid = blockIdx.x;                 // 4096 windows
    const int b   = wid >> 10;
    const int wy  = (wid >> 5) & 31;
    const int wx  = wid & 31;
    const int base0 = (b * 65536 + wy * 8 * 256 + wx * 8) * CDIM;

    // ---------------- stage x window (64 tok x 192 f32 -> bf16 LDS) ----------------
    #pragma unroll
    for (int r = 0; r < 6; ++r) {
        int i = tid + r * 512;                  // 3072 x float4 chunks
        int t = i / 48, part = i - t * 48;
        int iy = t >> 3, ix = t & 7;
        f32x4 v = *(const f32x4*)(x + base0 + (iy * 256 + ix) * CDIM + part * 4);
        u16x4 h;
        h[0] = f2b(v[0]); h[1] = f2b(v[1]); h[2] = f2b(v[2]); h[3] = f2b(v[3]);
        *(u16x4*)(xl + t * XS + part * 4) = h;
    }
    __syncthreads();

    // ---------------- QKV GEMM: (64x192)@(192x576) ----------------
    {
        const int wm = wv >> 2, wn = wv & 3;
        f32x4 acc[2][9];
        #pragma unroll
        for (int im = 0; im < 2; ++im)
            #pragma unroll
            for (int jn = 0; jn < 9; ++jn)
                acc[im][jn] = (f32x4){0.f, 0.f, 0.f, 0.f};

        #pragma unroll
        for (int kk = 0; kk < 6; ++kk) {
            bf16x8 aa[2];
            #pragma unroll
            for (int im = 0; im < 2; ++im)
                aa[im] = *(const bf16x8*)(xl + ((wm * 2 + im) * 16 + l15) * XS + kk * 32 + g8);
            #pragma unroll
            for (int jn = 0; jn < 9; ++jn) {
                int o = (wn * 9 + jn) * 16 + l15;
                bf16x8 bw = *(const bf16x8*)(qkv_w + o * CDIM + kk * 32 + g8);
                #pragma unroll
                for (int im = 0; im < 2; ++im)
                    acc[im][jn] = __builtin_amdgcn_mfma_f32_16x16x32_bf16(aa[im], bw, acc[im][jn], 0, 0, 0);
            }
        }
        #pragma unroll
        for (int jn = 0; jn < 9; ++jn) {
            int nt = wn * 9 + jn;               // 0..35
            int o  = nt * 16 + l15;             // 0..575
            float qb = qkv_b[o];
            #pragma unroll
            for (int im = 0; im < 2; ++im) {
                #pragma unroll
                for (int rr = 0; rr < 4; ++rr) {
                    int tr = (wm * 2 + im) * 16 + g * 4 + rr;
                    float val = acc[im][jn][rr] + qb;
                    if (nt < 24) qk[tr * QKS + o] = f2b(val);           // q | k
                    else         vt[(o - 384) * VTS + tr] = f2b(val);   // v^T
                }
            }
        }
    }
    __syncthreads();

    // ---------------- attention: 24 units = 6 heads x 4 row-blocks ----------------
    #pragma unroll
    for (int u = 0; u < 3; ++u) {
        int gu = wv * 3 + u;
        int hu = gu >> 2;
        int rb = gu & 3;
        unsigned short* Pw = pl + wv * (16 * PS);

        bf16x8 aq = *(const bf16x8*)(qk + (rb * 16 + l15) * QKS + hu * 32 + g8);
        f32x4 sacc[4];
        #pragma unroll
        for (int ni = 0; ni < 4; ++ni) {
            bf16x8 bk = *(const bf16x8*)(qk + (ni * 16 + l15) * QKS + 192 + hu * 32 + g8);
            sacc[ni] = __builtin_amdgcn_mfma_f32_16x16x32_bf16(aq, bk, (f32x4){0.f, 0.f, 0.f, 0.f}, 0, 0, 0);
        }

        const float* brow = bias + hu * 4096;
        #pragma unroll
        for (int rr = 0; rr < 4; ++rr) {
            int row = rb * 16 + g * 4 + rr;
            float v0 = sacc[0][rr] * SCALE + brow[row * 64 +  0 + l15];
            float v1 = sacc[1][rr] * SCALE + brow[row * 64 + 16 + l15];
            float v2 = sacc[2][rr] * SCALE + brow[row * 64 + 32 + l15];
            float v3 = sacc[3][rr] * SCALE + brow[row * 64 + 48 + l15];
            float m = fmaxf(fmaxf(v0, v1), fmaxf(v2, v3));
            m = fmaxf(m, __shfl_xor(m, 1));
            m = fmaxf(m, __shfl_xor(m, 2));
            m = fmaxf(m, __shfl_xor(m, 4));
            m = fmaxf(m, __shfl_xor(m, 8));
            v0 = __expf(v0 - m); v1 = __expf(v1 - m);
            v2 = __expf(v2 - m); v3 = __expf(v3 - m);
            float s = v0 + v1 + v2 + v3;
            s += __shfl_xor(s, 1); s += __shfl_xor(s, 2);
            s += __shfl_xor(s, 4); s += __shfl_xor(s, 8);
            float inv = 1.0f / s;
            int pr = (g * 4 + rr) * PS;
            Pw[pr +  0 + l15] = f2b(v0 * inv);
            Pw[pr + 16 + l15] = f2b(v1 * inv);
            Pw[pr + 32 + l15] = f2b(v2 * inv);
            Pw[pr + 48 + l15] = f2b(v3 * inv);
        }
        __threadfence_block();   // P visible to whole wave before PV reads

        f32x4 oacc[2];
        oacc[0] = (f32x4){0.f, 0.f, 0.f, 0.f};
        oacc[1] = (f32x4){0.f, 0.f, 0.f, 0.f};
        #pragma unroll
        for (int kk = 0; kk < 2; ++kk) {
            bf16x8 pa = *(const bf16x8*)(Pw + l15 * PS + kk * 32 + g8);
            #pragma unroll
            for (int nj = 0; nj < 2; ++nj) {
                bf16x8 bv = *(const bf16x8*)(vt + (hu * 32 + nj * 16 + l15) * VTS + kk * 32 + g8);
                oacc[nj] = __builtin_amdgcn_mfma_f32_16x16x32_bf16(pa, bv, oacc[nj], 0, 0, 0);
            }
        }
        #pragma unroll
        for (int nj = 0; nj < 2; ++nj)
            #pragma unroll
            for (int rr = 0; rr < 4; ++rr)
                ao[(rb * 16 + g * 4 + rr) * AOS + hu * 32 + nj * 16 + l15] = f2b(oacc[nj][rr]);
    }
    __syncthreads();

    // ---------------- proj GEMM: (64x192)@(192x192), f32 result to LDS ----------------
    {
        const int wm = wv >> 2, wn = wv & 3;
        f32x4 pacc[2][3];
        #pragma unroll
        for (int im = 0; im < 2; ++im)
            #pragma unroll
            for (int jn = 0; jn < 3; ++jn)
                pacc[im][jn] = (f32x4){0.f, 0.f, 0.f, 0.f};

        #pragma unroll
        for (int kk = 0; kk < 6; ++kk) {
            bf16x8 aa[2];
            #pragma unroll
            for (int im = 0; im < 2; ++im)
                aa[im] = *(const bf16x8*)(ao + ((wm * 2 + im) * 16 + l15) * AOS + kk * 32 + g8);
            #pragma unroll
            for (int jn = 0; jn < 3; ++jn) {
                int o = (wn * 3 + jn) * 16 + l15;
                bf16x8 bw = *(const bf16x8*)(proj_w + o * CDIM + kk * 32 + g8);
                #pragma unroll
                for (int im = 0; im < 2; ++im)
                    pacc[im][jn] = __builtin_amdgcn_mfma_f32_16x16x32_bf16(aa[im], bw, pacc[im][jn], 0, 0, 0);
            }
        }
        __syncthreads();   // everyone done reading qk-region? (qk dead since attn) -- protects outf alias vs attn-phase stragglers via the barrier above; this one orders ao reads before outf writes overlap region? outf only aliases qk, ao reads already done per-wave before stores below
        #pragma unroll
        for (int jn = 0; jn < 3; ++jn) {
            int o = (wn * 3 + jn) * 16 + l15;
            float pb = proj_b[o];
            #pragma unroll
            for (int im = 0; im < 2; ++im)
                #pragma unroll
                for (int rr = 0; rr < 4; ++rr) {
                    int tr = (wm * 2 + im) * 16 + g * 4 + rr;
                    outf[tr * OFS + o] = pacc[im][jn][rr] + pb;
                }
        }
    }
    __syncthreads();

    // ---------------- window-reverse coalesced f32 store ----------------
    #pragma unroll
    for (int r = 0; r < 6; ++r) {
        int i = tid + r * 512;
        int t = i / 48, part = i - t * 48;
        int iy = t >> 3, ix = t & 7;
        *(f32x4*)(out + base0 + (iy * 256 + ix) * CDIM + part * 4) =
            *(const f32x4*)(outf + t * OFS + part * 4);
    }
}

extern "C" void kernel_launch(void* const* d_in, const int* in_sizes, int n_in,
                              void* d_out, int out_size, void* d_ws, size_t ws_size,
                              hipStream_t stream) {
    const float* x      = (const float*)d_in[0];
    const float* qkv_w  = (const float*)d_in[1];
    const float* qkv_b  = (const float*)d_in[2];
    const float* proj_w = (const float*)d_in[3];
    const float* proj_b = (const float*)d_in[4];
    const float* rpb    = (const float*)d_in[5];
    float* outp = (float*)d_out;

    char* ws = (char*)d_ws;
    unsigned short* W1 = (unsigned short*)(ws + WS_W1);
    unsigned short* W2 = (unsigned short*)(ws + WS_W2);
    float* B1   = (float*)(ws + WS_B1);
    float* B2   = (float*)(ws + WS_B2);
    float* BIAS = (float*)(ws + WS_BIAS);

    hipFuncSetAttribute((const void*)win_attn,
                        hipFuncAttributeMaxDynamicSharedMemorySize, SMEM_BYTES);

    prep<<<675, 256, 0, stream>>>(qkv_w, qkv_b, proj_w, proj_b, rpb, W1, W2, B1, B2, BIAS);
    win_attn<<<4096, 512, SMEM_BYTES, stream>>>(x, W1, B1, W2, B2, BIAS, outp);
}